// Round 2
// baseline (307.145 us; speedup 1.0000x reference)
//
#include <hip/hip_runtime.h>
#include <hip/hip_fp16.h>
#include <stdint.h>

#define K_DIM 4096
#define N_OUT 4096
#define BM 128
#define BN 128
#define BKB 128  // K-bytes staged per step

typedef __attribute__((ext_vector_type(4))) int int32x4;
typedef __attribute__((ext_vector_type(16))) int int32x16;

// ---------------- per-token int4 activation quantization ----------------
// Reference (np, high internal precision): x_scale = max(x_max/7, fp16(1e-5));
// x_q = clip(rint(x / x_scale), -8, 7). All in f32 here; no intermediate fp16
// rounding (the harness's np ref computes at >= f32 precision on the
// upconverted inputs and only rounds the final output to fp16).
__global__ __launch_bounds__(256) void quant_x(const float* __restrict__ x,
                                               int8_t* __restrict__ xq,
                                               float* __restrict__ xs) {
  const int row = blockIdx.x;
  const int t = threadIdx.x;
  const float4* xr = (const float4*)(x + (size_t)row * K_DIM);
  float4 v[4];
  float m = 0.f;
#pragma unroll
  for (int i = 0; i < 4; ++i) {
    v[i] = xr[t * 4 + i];
    m = fmaxf(m, fmaxf(fmaxf(fabsf(v[i].x), fabsf(v[i].y)),
                       fmaxf(fabsf(v[i].z), fabsf(v[i].w))));
  }
#pragma unroll
  for (int off = 32; off > 0; off >>= 1) m = fmaxf(m, __shfl_xor(m, off));
  __shared__ float wmax[4];
  if ((t & 63) == 0) wmax[t >> 6] = m;
  __syncthreads();
  m = fmaxf(fmaxf(wmax[0], wmax[1]), fmaxf(wmax[2], wmax[3]));

  // fp16(1e-5) value = 168 * 2^-24 (the half constant, promoted to f32)
  const float eps = 1.0013580322265625e-05f;
  const float xscale = fmaxf(m / 7.0f, eps);  // f32, no fp16 rounding
  if (t == 0) xs[row] = xscale;

  uint32_t p[4];
#pragma unroll
  for (int g = 0; g < 4; ++g) {
    const float* fv = (const float*)&v[g];
    uint32_t w = 0;
#pragma unroll
    for (int j = 0; j < 4; ++j) {
      float r = rintf(fv[j] / xscale);  // f32 quotient, round-half-even
      r = fminf(fmaxf(r, -8.f), 7.f);
      w |= ((uint32_t)(uint8_t)(int8_t)(int)r) << (8 * j);
    }
    p[g] = w;
  }
  *(uint4*)(xq + (size_t)row * K_DIM + t * 16) = *(uint4*)p;
}

// ---------------- weight int32 -> int8 pack ----------------
__global__ __launch_bounds__(256) void pack_w(const int* __restrict__ w,
                                              uint32_t* __restrict__ wq) {
  int i = blockIdx.x * 256 + threadIdx.x;
  const int4 v = ((const int4*)w)[i];
  wq[i] = (uint32_t)(v.x & 255) | ((uint32_t)(v.y & 255) << 8) |
          ((uint32_t)(v.z & 255) << 16) | ((uint32_t)(v.w & 255) << 24);
}

// ---------------- i8 GEMM: out[m][n] = sum_k xq[m][k]*wq[n][k], dequant -----
// 128x128 tile, 4 waves (2x2), 32x32x32 i8 MFMA, BK=128B, LDS double-buffered.
// LDS layout is FRAGMENT-CONTIGUOUS: each (frag, kblk) is a 1024B block laid
// out exactly in MFMA lane order, so ds_read_b128 at base+lane*16 is
// conflict-free, and global_load_lds (wave-uniform base + lane*16) writes it
// directly by giving each lane the right (row, kchunk) global address.
__global__ __launch_bounds__(256, 2) void gemm_w4a4(
    const int8_t* __restrict__ xq, const int8_t* __restrict__ wq,
    const float* __restrict__ xs, const float* __restrict__ wscale,
    float* __restrict__ out, int M) {
  __shared__ uint8_t lds[2][32768];  // [buf][A:16KB | B:16KB]

  // XCD-aware swizzle (grid = 2048, divisible by 8)
  const int nwg = gridDim.x;
  const int cpx = nwg >> 3;
  const int bid = blockIdx.x;
  const int swz = (bid & 7) * cpx + (bid >> 3);
  const int mtiles = M / BM;
  const int mt = swz % mtiles;
  const int nt = swz / mtiles;
  const int tm = mt * BM;
  const int tn = nt * BN;

  const int t = threadIdx.x;
  const int l = t & 63;
  const int wv = t >> 6;

  // staging: issue j covers frag rows j*32..j*32+31, kblk = wv
  const int srow = l & 31;
  const int skoff = wv * 32 + ((l >> 5) << 4);
  const uint8_t* gA = (const uint8_t*)xq + (size_t)(tm + srow) * K_DIM + skoff;
  const uint8_t* gB = (const uint8_t*)wq + (size_t)(tn + srow) * K_DIM + skoff;

  int32x16 acc[2][2] = {};

  const int wm = wv >> 1, wn = wv & 1;

  auto stage = [&](int buf, int ktb) {
#pragma unroll
    for (int j = 0; j < 4; ++j) {
      __builtin_amdgcn_global_load_lds(
          (const __attribute__((address_space(1))) uint32_t*)(gA + (size_t)ktb + (size_t)j * 32 * K_DIM),
          (__attribute__((address_space(3))) uint32_t*)(&lds[buf][j * 4096 + t * 16]),
          16, 0, 0);
    }
#pragma unroll
    for (int j = 0; j < 4; ++j) {
      __builtin_amdgcn_global_load_lds(
          (const __attribute__((address_space(1))) uint32_t*)(gB + (size_t)ktb + (size_t)j * 32 * K_DIM),
          (__attribute__((address_space(3))) uint32_t*)(&lds[buf][16384 + j * 4096 + t * 16]),
          16, 0, 0);
    }
  };

  stage(0, 0);
  asm volatile("s_waitcnt vmcnt(0)" ::: "memory");
  __syncthreads();

  const int nsteps = K_DIM / BKB;  // 32
  int cur = 0;
  for (int s = 0; s < nsteps; ++s) {
    if (s + 1 < nsteps) stage(cur ^ 1, (s + 1) * BKB);  // prefetch next tile

    const uint8_t* lA = &lds[cur][0] + (wm * 2) * 4096 + l * 16;
    const uint8_t* lB = &lds[cur][16384] + (wn * 2) * 4096 + l * 16;
#pragma unroll
    for (int kb = 0; kb < 4; ++kb) {
      int32x4 a0 = *(const int32x4*)(lA + kb * 1024);
      int32x4 a1 = *(const int32x4*)(lA + 4096 + kb * 1024);
      int32x4 b0 = *(const int32x4*)(lB + kb * 1024);
      int32x4 b1 = *(const int32x4*)(lB + 4096 + kb * 1024);
      acc[0][0] = __builtin_amdgcn_mfma_i32_32x32x32_i8(a0, b0, acc[0][0], 0, 0, 0);
      acc[0][1] = __builtin_amdgcn_mfma_i32_32x32x32_i8(a0, b1, acc[0][1], 0, 0, 0);
      acc[1][0] = __builtin_amdgcn_mfma_i32_32x32x32_i8(a1, b0, acc[1][0], 0, 0, 0);
      acc[1][1] = __builtin_amdgcn_mfma_i32_32x32x32_i8(a1, b1, acc[1][1], 0, 0, 0);
    }

    asm volatile("s_waitcnt vmcnt(0)" ::: "memory");
    __syncthreads();
    cur ^= 1;
  }

  // epilogue: dequant + fp16-round, write f32
  const int colbase = tn + wn * 64;
  const int rowbase = tm + wm * 64 + 4 * (l >> 5);
#pragma unroll
  for (int a = 0; a < 2; ++a) {
#pragma unroll
    for (int b = 0; b < 2; ++b) {
      const int col = colbase + b * 32 + (l & 31);
      const float wsc = wscale[col];
#pragma unroll
      for (int j = 0; j < 16; ++j) {
        const int row = rowbase + a * 32 + (j & 3) + 8 * (j >> 2);
        const float val = (float)acc[a][b][j] * (xs[row] * wsc);
        out[(size_t)row * N_OUT + col] = __half2float(__float2half(val));
      }
    }
  }
}

extern "C" void kernel_launch(void* const* d_in, const int* in_sizes, int n_in,
                              void* d_out, int out_size, void* d_ws, size_t ws_size,
                              hipStream_t stream) {
  const float* x = (const float*)d_in[0];       // fp16 values as f32
  const int* w = (const int*)d_in[1];           // int4-range values as i32
  const float* wsc = (const float*)d_in[2];     // fp16 values as f32
  float* out = (float*)d_out;

  const int M = in_sizes[0] / K_DIM;  // 8192 tokens

  uint8_t* ws = (uint8_t*)d_ws;
  int8_t* xq = (int8_t*)ws;                                   // M*K bytes
  uint8_t* wq = ws + (size_t)M * K_DIM;                       // N*K bytes
  float* xs = (float*)(ws + (size_t)M * K_DIM + (size_t)N_OUT * K_DIM);

  quant_x<<<M, 256, 0, stream>>>(x, xq, xs);
  pack_w<<<(N_OUT * (K_DIM / 4)) / 256, 256, 0, stream>>>(w, (uint32_t*)wq);
  gemm_w4a4<<<(M / BM) * (N_OUT / BN), 256, 0, stream>>>(
      xq, (const int8_t*)wq, xs, wsc, out, M);
}

// Round 3
// 289.433 us; speedup vs baseline: 1.0612x; 1.0612x over previous
//
#include <hip/hip_runtime.h>
#include <hip/hip_fp16.h>
#include <stdint.h>

#define K_DIM 4096
#define N_OUT 4096
#define BM 128
#define BN 128
#define BKB 128  // K-bytes staged per step

typedef __attribute__((ext_vector_type(4))) int int32x4;
typedef __attribute__((ext_vector_type(16))) int int32x16;

// ---------------- per-token int4 activation quantization ----------------
// Reference (np, high internal precision): x_scale = max(x_max/7, fp16(1e-5));
// x_q = clip(rint(x / x_scale), -8, 7). All f32; no intermediate fp16 rounding.
__global__ __launch_bounds__(256) void quant_x(const float* __restrict__ x,
                                               int8_t* __restrict__ xq,
                                               float* __restrict__ xs) {
  const int row = blockIdx.x;
  const int t = threadIdx.x;
  const float4* xr = (const float4*)(x + (size_t)row * K_DIM);
  float4 v[4];
  float m = 0.f;
#pragma unroll
  for (int i = 0; i < 4; ++i) {
    v[i] = xr[t * 4 + i];
    m = fmaxf(m, fmaxf(fmaxf(fabsf(v[i].x), fabsf(v[i].y)),
                       fmaxf(fabsf(v[i].z), fabsf(v[i].w))));
  }
#pragma unroll
  for (int off = 32; off > 0; off >>= 1) m = fmaxf(m, __shfl_xor(m, off));
  __shared__ float wmax[4];
  if ((t & 63) == 0) wmax[t >> 6] = m;
  __syncthreads();
  m = fmaxf(fmaxf(wmax[0], wmax[1]), fmaxf(wmax[2], wmax[3]));

  // fp16(1e-5) value = 168 * 2^-24 (the half constant, promoted to f32)
  const float eps = 1.0013580322265625e-05f;
  const float xscale = fmaxf(m / 7.0f, eps);  // f32, no fp16 rounding
  if (t == 0) xs[row] = xscale;

  uint32_t p[4];
#pragma unroll
  for (int g = 0; g < 4; ++g) {
    const float* fv = (const float*)&v[g];
    uint32_t w = 0;
#pragma unroll
    for (int j = 0; j < 4; ++j) {
      float r = rintf(fv[j] / xscale);  // f32 quotient, round-half-even
      r = fminf(fmaxf(r, -8.f), 7.f);
      w |= ((uint32_t)(uint8_t)(int8_t)(int)r) << (8 * j);
    }
    p[g] = w;
  }
  *(uint4*)(xq + (size_t)row * K_DIM + t * 16) = *(uint4*)p;
}

// ---------------- weight int32 -> int8 pack ----------------
__global__ __launch_bounds__(256) void pack_w(const int* __restrict__ w,
                                              uint32_t* __restrict__ wq) {
  int i = blockIdx.x * 256 + threadIdx.x;
  const int4 v = ((const int4*)w)[i];
  wq[i] = (uint32_t)(v.x & 255) | ((uint32_t)(v.y & 255) << 8) |
          ((uint32_t)(v.z & 255) << 16) | ((uint32_t)(v.w & 255) << 24);
}

// ---------------- i8 GEMM: out[m][n] = sum_k xq[m][k]*wq[n][k], dequant -----
// 128x128 tile, 4 waves (2x2), 32x32x32 i8 MFMA, BK=128B.
// LDS fragment-contiguous layout (validated r2): each (frag,kblk) is a 1024B
// block in MFMA lane order; ds_read_b128 at base+lane*16 is conflict-free and
// global_load_lds writes it directly (per-lane global source addresses).
// Main loop: counted-vmcnt double buffer (T3/T4) — next tile's 8 loads issued
// first, s_waitcnt vmcnt(8) waits only the CURRENT buffer's loads (issued one
// full compute-phase earlier), raw s_barrier; second barrier guards the WAR
// on re-staging. vmcnt never drains to 0 in the main loop.
__global__ __launch_bounds__(256, 2) void gemm_w4a4(
    const int8_t* __restrict__ xq, const int8_t* __restrict__ wq,
    const float* __restrict__ xs, const float* __restrict__ wscale,
    float* __restrict__ out, int M) {
  __shared__ uint8_t lds[2][32768];  // [buf][A:16KB | B:16KB]

  // XCD-aware swizzle with intra-XCD A-panel reuse: each XCD owns a
  // contiguous 4-wide nt strip; 4 consecutive local blocks share one A panel
  // so concurrent blocks hit the same A lines in L2.
  const int bid = blockIdx.x;
  const int xcd = bid & 7;
  const int i_loc = bid >> 3;          // 0..255
  const int mt = i_loc >> 2;           // 0..63
  const int nt = xcd * 4 + (i_loc & 3);  // 0..31
  const int tm = mt * BM;
  const int tn = nt * BN;

  const int t = threadIdx.x;
  const int l = t & 63;
  const int wv = t >> 6;

  // staging: issue j covers frag rows j*32..j*32+31, kblk = wv
  const int srow = l & 31;
  const int skoff = wv * 32 + ((l >> 5) << 4);
  const uint8_t* gA = (const uint8_t*)xq + (size_t)(tm + srow) * K_DIM + skoff;
  const uint8_t* gB = (const uint8_t*)wq + (size_t)(tn + srow) * K_DIM + skoff;

  int32x16 acc[2][2] = {};

  const int wm = wv >> 1, wn = wv & 1;

  auto stage = [&](int buf, int ktb) {
#pragma unroll
    for (int j = 0; j < 4; ++j) {
      __builtin_amdgcn_global_load_lds(
          (const __attribute__((address_space(1))) uint32_t*)(gA + (size_t)ktb + (size_t)j * 32 * K_DIM),
          (__attribute__((address_space(3))) uint32_t*)(&lds[buf][j * 4096 + t * 16]),
          16, 0, 0);
    }
#pragma unroll
    for (int j = 0; j < 4; ++j) {
      __builtin_amdgcn_global_load_lds(
          (const __attribute__((address_space(1))) uint32_t*)(gB + (size_t)ktb + (size_t)j * 32 * K_DIM),
          (__attribute__((address_space(3))) uint32_t*)(&lds[buf][16384 + j * 4096 + t * 16]),
          16, 0, 0);
    }
  };

  auto compute = [&](int buf) {
    const uint8_t* lA = &lds[buf][0] + (wm * 2) * 4096 + l * 16;
    const uint8_t* lB = &lds[buf][16384] + (wn * 2) * 4096 + l * 16;
    __builtin_amdgcn_s_setprio(1);
#pragma unroll
    for (int kb = 0; kb < 4; ++kb) {
      int32x4 a0 = *(const int32x4*)(lA + kb * 1024);
      int32x4 a1 = *(const int32x4*)(lA + 4096 + kb * 1024);
      int32x4 b0 = *(const int32x4*)(lB + kb * 1024);
      int32x4 b1 = *(const int32x4*)(lB + 4096 + kb * 1024);
      acc[0][0] = __builtin_amdgcn_mfma_i32_32x32x32_i8(a0, b0, acc[0][0], 0, 0, 0);
      acc[0][1] = __builtin_amdgcn_mfma_i32_32x32x32_i8(a0, b1, acc[0][1], 0, 0, 0);
      acc[1][0] = __builtin_amdgcn_mfma_i32_32x32x32_i8(a1, b0, acc[1][0], 0, 0, 0);
      acc[1][1] = __builtin_amdgcn_mfma_i32_32x32x32_i8(a1, b1, acc[1][1], 0, 0, 0);
    }
    __builtin_amdgcn_s_setprio(0);
  };

  const int nsteps = K_DIM / BKB;  // 32

  stage(0, 0);  // 8 loads in flight
  int cur = 0;
  for (int s = 0; s < nsteps - 1; ++s) {
    stage(cur ^ 1, (s + 1) * BKB);  // +8 loads -> 16 in flight
    // wait until only the 8 just-issued remain -> buf[cur] fully landed
    asm volatile("s_waitcnt vmcnt(8)" ::: "memory");
    __builtin_amdgcn_s_barrier();   // all waves' buf[cur] loads landed
    compute(cur);
    __builtin_amdgcn_s_barrier();   // all waves done reading buf[cur] (WAR)
    cur ^= 1;
  }
  asm volatile("s_waitcnt vmcnt(0)" ::: "memory");
  __builtin_amdgcn_s_barrier();
  compute(cur);

  // epilogue: dequant + fp16-round, write f32
  const int colbase = tn + wn * 64;
  const int rowbase = tm + wm * 64 + 4 * (l >> 5);
#pragma unroll
  for (int a = 0; a < 2; ++a) {
#pragma unroll
    for (int b = 0; b < 2; ++b) {
      const int col = colbase + b * 32 + (l & 31);
      const float wsc = wscale[col];
#pragma unroll
      for (int j = 0; j < 16; ++j) {
        const int row = rowbase + a * 32 + (j & 3) + 8 * (j >> 2);
        const float val = (float)acc[a][b][j] * (xs[row] * wsc);
        out[(size_t)row * N_OUT + col] = __half2float(__float2half(val));
      }
    }
  }
}

extern "C" void kernel_launch(void* const* d_in, const int* in_sizes, int n_in,
                              void* d_out, int out_size, void* d_ws, size_t ws_size,
                              hipStream_t stream) {
  const float* x = (const float*)d_in[0];       // fp16 values as f32
  const int* w = (const int*)d_in[1];           // int4-range values as i32
  const float* wsc = (const float*)d_in[2];     // fp16 values as f32
  float* out = (float*)d_out;

  const int M = in_sizes[0] / K_DIM;  // 8192 tokens

  uint8_t* ws = (uint8_t*)d_ws;
  int8_t* xq = (int8_t*)ws;                                   // M*K bytes
  uint8_t* wq = ws + (size_t)M * K_DIM;                       // N*K bytes
  float* xs = (float*)(ws + (size_t)M * K_DIM + (size_t)N_OUT * K_DIM);

  quant_x<<<M, 256, 0, stream>>>(x, xq, xs);
  pack_w<<<(N_OUT * (K_DIM / 4)) / 256, 256, 0, stream>>>(w, (uint32_t*)wq);
  gemm_w4a4<<<(M / BM) * (N_OUT / BN), 256, 0, stream>>>(
      xq, (const int8_t*)wq, xs, wsc, out, M);
}

// Round 4
// 249.555 us; speedup vs baseline: 1.2308x; 1.1598x over previous
//
#include <hip/hip_runtime.h>
#include <hip/hip_fp16.h>
#include <stdint.h>

#define K_DIM 4096
#define N_OUT 4096
#define BM 256
#define BN 128
#define BKB 64  // K-bytes staged per step (64 i8 elems = 2 MFMA K-slices)

typedef __attribute__((ext_vector_type(4))) int int32x4;
typedef __attribute__((ext_vector_type(16))) int int32x16;

// ---------------- per-token int4 activation quantization ----------------
// Reference (np, high internal precision): x_scale = max(x_max/7, fp16(1e-5));
// x_q = clip(rint(x / x_scale), -8, 7). All f32; no intermediate fp16 rounding.
__global__ __launch_bounds__(256) void quant_x(const float* __restrict__ x,
                                               int8_t* __restrict__ xq,
                                               float* __restrict__ xs) {
  const int row = blockIdx.x;
  const int t = threadIdx.x;
  const float4* xr = (const float4*)(x + (size_t)row * K_DIM);
  float4 v[4];
  float m = 0.f;
#pragma unroll
  for (int i = 0; i < 4; ++i) {
    v[i] = xr[t * 4 + i];
    m = fmaxf(m, fmaxf(fmaxf(fabsf(v[i].x), fabsf(v[i].y)),
                       fmaxf(fabsf(v[i].z), fabsf(v[i].w))));
  }
#pragma unroll
  for (int off = 32; off > 0; off >>= 1) m = fmaxf(m, __shfl_xor(m, off));
  __shared__ float wmax[4];
  if ((t & 63) == 0) wmax[t >> 6] = m;
  __syncthreads();
  m = fmaxf(fmaxf(wmax[0], wmax[1]), fmaxf(wmax[2], wmax[3]));

  // fp16(1e-5) value = 168 * 2^-24 (the half constant, promoted to f32)
  const float eps = 1.0013580322265625e-05f;
  const float xscale = fmaxf(m / 7.0f, eps);  // f32, no fp16 rounding
  if (t == 0) xs[row] = xscale;

  uint32_t p[4];
#pragma unroll
  for (int g = 0; g < 4; ++g) {
    const float* fv = (const float*)&v[g];
    uint32_t w = 0;
#pragma unroll
    for (int j = 0; j < 4; ++j) {
      float r = rintf(fv[j] / xscale);  // f32 quotient, round-half-even
      r = fminf(fmaxf(r, -8.f), 7.f);
      w |= ((uint32_t)(uint8_t)(int8_t)(int)r) << (8 * j);
    }
    p[g] = w;
  }
  *(uint4*)(xq + (size_t)row * K_DIM + t * 16) = *(uint4*)p;
}

// ---------------- weight int32 -> int8 pack ----------------
__global__ __launch_bounds__(256) void pack_w(const int* __restrict__ w,
                                              uint32_t* __restrict__ wq) {
  int i = blockIdx.x * 256 + threadIdx.x;
  const int4 v = ((const int4*)w)[i];
  wq[i] = (uint32_t)(v.x & 255) | ((uint32_t)(v.y & 255) << 8) |
          ((uint32_t)(v.z & 255) << 16) | ((uint32_t)(v.w & 255) << 24);
}

// ---------------- i8 GEMM: out[m][n] = sum_k xq[m][k]*wq[n][k], dequant -----
// 256x128 tile, 4 waves (2M x 2N), wave tile 128x64 (4m x 2n frags of 32x32),
// 32x32x32 i8 MFMA, BK=64B, 3-deep LDS pipeline (24KB/buf), counted vmcnt(6).
// LDS fragment-contiguous layout (validated r2/r3): each (frag,kb) is a 1024B
// block in MFMA lane order; ds_read_b128 at base+lane*16 is conflict-free and
// global_load_lds writes it directly (per-lane global source addresses).
// Per step: 2 phases of {ds_read 6 || stage-issue -> barrier -> 8 MFMA
// (setprio) -> barrier}. vmcnt(6) once per step (never 0 in steady state):
// loads are issued 2 full steps ahead of use.
__global__ __launch_bounds__(256, 2) void gemm_w4a4(
    const int8_t* __restrict__ xq, const int8_t* __restrict__ wq,
    const float* __restrict__ xs, const float* __restrict__ wscale,
    float* __restrict__ out, int M) {
  __shared__ uint8_t lds[3][24576];  // [buf][A:16KB | B:8KB]

  // XCD swizzle: each XCD owns nmt/8 A-panels; within XCD, nt varies fastest
  // so a panel's 32 consumers are consecutive -> A stays L2-resident.
  const int bid = blockIdx.x;
  const int xcd = bid & 7;
  const int i_loc = bid >> 3;
  const int nmt = M / BM;
  const int mt = xcd * (nmt >> 3) + (i_loc >> 5);
  const int nt = i_loc & 31;
  const int tm = mt * BM;
  const int tn = nt * BN;

  const int t = threadIdx.x;
  const int l = t & 63;
  const int wv = t >> 6;
  const int wm = wv >> 1, wn = wv & 1;

  // per-lane global staging offset: lane l covers row (l&31), k-bytes (l>>5)*16
  const size_t laneoff = (size_t)(l & 31) * K_DIM + ((l >> 5) << 4);
  const uint8_t* gA = (const uint8_t*)xq + (size_t)tm * K_DIM + laneoff;
  const uint8_t* gB = (const uint8_t*)wq + (size_t)tn * K_DIM + laneoff;

  int32x16 acc[4][2] = {};

  // A: 16 blocks (fa 0..7 x kb 0..1), bIdx = j*4+wv; B: 8 blocks, same scheme.
  auto stage = [&](int buf, int ktb) {
#pragma unroll
    for (int j = 0; j < 4; ++j) {
      const int bIdx = j * 4 + wv;
      const int fa = bIdx >> 1, kb = bIdx & 1;
      __builtin_amdgcn_global_load_lds(
          (const __attribute__((address_space(1))) uint32_t*)(
              gA + (size_t)(fa * 32) * K_DIM + kb * 32 + ktb),
          (__attribute__((address_space(3))) uint32_t*)(
              &lds[buf][j * 4096 + t * 16]),
          16, 0, 0);
    }
#pragma unroll
    for (int j = 0; j < 2; ++j) {
      const int bIdx = j * 4 + wv;
      const int fb = bIdx >> 1, kb = bIdx & 1;
      __builtin_amdgcn_global_load_lds(
          (const __attribute__((address_space(1))) uint32_t*)(
              gB + (size_t)(fb * 32) * K_DIM + kb * 32 + ktb),
          (__attribute__((address_space(3))) uint32_t*)(
              &lds[buf][16384 + j * 4096 + t * 16]),
          16, 0, 0);
    }
  };

  // one phase: read 6 frags (kb slice), MFMA 8 between barrier pair
  auto phase = [&](int buf, int kb) {
    const uint8_t* Ab = &lds[buf][0] + (wm * 8 + kb) * 1024 + l * 16;
    const uint8_t* Bb = &lds[buf][16384] + (wn * 4 + kb) * 1024 + l * 16;
    int32x4 a[4], b[2];
#pragma unroll
    for (int m = 0; m < 4; ++m) a[m] = *(const int32x4*)(Ab + m * 2048);
#pragma unroll
    for (int n = 0; n < 2; ++n) b[n] = *(const int32x4*)(Bb + n * 2048);
    __builtin_amdgcn_s_barrier();
    __builtin_amdgcn_s_setprio(1);
#pragma unroll
    for (int m = 0; m < 4; ++m)
#pragma unroll
      for (int n = 0; n < 2; ++n)
        acc[m][n] =
            __builtin_amdgcn_mfma_i32_32x32x32_i8(a[m], b[n], acc[m][n], 0, 0, 0);
    __builtin_amdgcn_s_setprio(0);
    __builtin_amdgcn_s_barrier();
  };

  const int nsteps = K_DIM / BKB;  // 64

  // prologue: 2 tiles in flight
  stage(0, 0);
  stage(1, BKB);
  asm volatile("s_waitcnt vmcnt(6)" ::: "memory");  // tile 0 landed
  __builtin_amdgcn_s_barrier();

  for (int s = 0; s < nsteps; ++s) {
    const int cur = s % 3;
    // phase 0: issue tile s+2 first (latency), then reads
    if (s + 2 < nsteps) stage((s + 2) % 3, (s + 2) * BKB);
    phase(cur, 0);
    phase(cur, 1);
    // tile s+1 must be landed before next step's ds_reads (all waves, then
    // the trailing barrier of phase 1 orders it block-wide... barrier is
    // inside phase(); place the wait before that barrier would be ideal, but
    // a dedicated wait+barrier here is equally correct:
    if (s < nsteps - 2)
      asm volatile("s_waitcnt vmcnt(6)" ::: "memory");  // oldest 6 = tile s+1
    else
      asm volatile("s_waitcnt vmcnt(0)" ::: "memory");
    __builtin_amdgcn_s_barrier();
  }

  // epilogue: dequant + fp16-round, write f32
  const int colbase = tn + wn * 64;
  const int rowbase = tm + wm * 128 + 4 * (l >> 5);
#pragma unroll
  for (int m = 0; m < 4; ++m) {
#pragma unroll
    for (int n = 0; n < 2; ++n) {
      const int col = colbase + n * 32 + (l & 31);
      const float wsc = wscale[col];
#pragma unroll
      for (int j = 0; j < 16; ++j) {
        const int row = rowbase + m * 32 + (j & 3) + 8 * (j >> 2);
        const float val = (float)acc[m][n][j] * (xs[row] * wsc);
        out[(size_t)row * N_OUT + col] = __half2float(__float2half(val));
      }
    }
  }
}

extern "C" void kernel_launch(void* const* d_in, const int* in_sizes, int n_in,
                              void* d_out, int out_size, void* d_ws, size_t ws_size,
                              hipStream_t stream) {
  const float* x = (const float*)d_in[0];    // fp16 values as f32
  const int* w = (const int*)d_in[1];        // int4-range values as i32
  const float* wsc = (const float*)d_in[2];  // fp16 values as f32
  float* out = (float*)d_out;

  const int M = in_sizes[0] / K_DIM;  // 8192 tokens

  uint8_t* ws = (uint8_t*)d_ws;
  int8_t* xq = (int8_t*)ws;                              // M*K bytes
  uint8_t* wq = ws + (size_t)M * K_DIM;                  // N*K bytes
  float* xs = (float*)(ws + (size_t)M * K_DIM + (size_t)N_OUT * K_DIM);

  quant_x<<<M, 256, 0, stream>>>(x, xq, xs);
  pack_w<<<(N_OUT * (K_DIM / 4)) / 256, 256, 0, stream>>>(w, (uint32_t*)wq);
  gemm_w4a4<<<(M / BM) * (N_OUT / BN), 256, 0, stream>>>(
      xq, (const int8_t*)wq, xs, wsc, out, M);
}

// Round 5
// 233.786 us; speedup vs baseline: 1.3138x; 1.0674x over previous
//
#include <hip/hip_runtime.h>
#include <hip/hip_fp16.h>
#include <stdint.h>

#define K_DIM 4096
#define N_OUT 4096
#define BM 256
#define BN 128
#define BKB 64  // K-bytes per step (2 MFMA K-slices)

typedef __attribute__((ext_vector_type(4))) int int32x4;
typedef __attribute__((ext_vector_type(16))) int int32x16;

// ---------------- per-token int4 activation quantization ----------------
// x_scale = max(x_max/7, fp16(1e-5)); x_q = clip(rint(x/x_scale), -8, 7).
// All f32; no intermediate fp16 rounding (matches harness np reference).
__global__ __launch_bounds__(256) void quant_x(const float* __restrict__ x,
                                               int8_t* __restrict__ xq,
                                               float* __restrict__ xs) {
  const int row = blockIdx.x;
  const int t = threadIdx.x;
  const float4* xr = (const float4*)(x + (size_t)row * K_DIM);
  float4 v[4];
  float m = 0.f;
#pragma unroll
  for (int i = 0; i < 4; ++i) {
    v[i] = xr[t * 4 + i];
    m = fmaxf(m, fmaxf(fmaxf(fabsf(v[i].x), fabsf(v[i].y)),
                       fmaxf(fabsf(v[i].z), fabsf(v[i].w))));
  }
#pragma unroll
  for (int off = 32; off > 0; off >>= 1) m = fmaxf(m, __shfl_xor(m, off));
  __shared__ float wmax[4];
  if ((t & 63) == 0) wmax[t >> 6] = m;
  __syncthreads();
  m = fmaxf(fmaxf(wmax[0], wmax[1]), fmaxf(wmax[2], wmax[3]));

  const float eps = 1.0013580322265625e-05f;  // fp16(1e-5) as f32
  const float xscale = fmaxf(m / 7.0f, eps);
  if (t == 0) xs[row] = xscale;

  uint32_t p[4];
#pragma unroll
  for (int g = 0; g < 4; ++g) {
    const float* fv = (const float*)&v[g];
    uint32_t w = 0;
#pragma unroll
    for (int j = 0; j < 4; ++j) {
      float r = rintf(fv[j] / xscale);
      r = fminf(fmaxf(r, -8.f), 7.f);
      w |= ((uint32_t)(uint8_t)(int8_t)(int)r) << (8 * j);
    }
    p[g] = w;
  }
  *(uint4*)(xq + (size_t)row * K_DIM + t * 16) = *(uint4*)p;
}

// ---------------- weight pack: int32 -> int8, FRAGMENT-MAJOR ----------------
// Output layout: block b = nfrag*128 + kslice (nfrag = n>>5, kslice = k>>5),
// each block 1024B in MFMA lane order: byte[l*16+j] = w[nfrag*32+(l&31)]
// [kslice*32+((l>>5)<<4)+j]. GEMM then loads B frags with coalesced
// global_load_dwordx4 at block*1024 + l*16 — no LDS for B at all.
__global__ __launch_bounds__(256) void pack_w(const int* __restrict__ w,
                                              uint32_t* __restrict__ wqf) {
  const int c = blockIdx.x * 256 + threadIdx.x;  // one thread per 16B chunk
  const int blk = c >> 6;
  const int l = c & 63;
  const int row = ((blk >> 7) << 5) + (l & 31);
  const int k = ((blk & 127) << 5) + ((l >> 5) << 4);
  const int4* src = (const int4*)(w + (size_t)row * K_DIM + k);  // 16 ints
  uint32_t p[4];
#pragma unroll
  for (int g = 0; g < 4; ++g) {
    const int4 v = src[g];
    p[g] = (uint32_t)(v.x & 255) | ((uint32_t)(v.y & 255) << 8) |
           ((uint32_t)(v.z & 255) << 16) | ((uint32_t)(v.w & 255) << 24);
  }
  *(uint4*)(wqf + (size_t)c * 4) = *(uint4*)p;
}

// ---------------- i8 GEMM: out = dequant(xq . wq^T) ----------------
// 256x128 tile, 4 waves (2m x 2n), wave tile 128x64, 32x32x32 i8 MFMA.
// A: LDS, fragment-contiguous, 3-deep pipeline, global_load_lds (16KB/step).
// B: fragment-major global -> registers, double-buffered 2 steps ahead,
//    coalesced dwordx4 (L2-resident per XCD via swizzle). No B in LDS.
// Per step: 8 VMEM ops (4 A-stage + 4 B); vmcnt(8) at step end retires
// exactly tile s+1's loads; ONE barrier per step. Prefetch wraps mod K so
// the vmcnt count stays uniform through the tail.
__global__ __launch_bounds__(256, 2) void gemm_w4a4(
    const int8_t* __restrict__ xq, const uint8_t* __restrict__ wqf,
    const float* __restrict__ xs, const float* __restrict__ wscale,
    float* __restrict__ out, int M) {
  __shared__ uint8_t lds[3][16384];  // A only: 16 frag-blocks/buf

  // r3 swizzle: each XCD owns a 4-wide nt strip (B panels 2MB, L2-resident);
  // 4 consecutive local blocks share one A panel.
  const int bid = blockIdx.x;
  const int xcd = bid & 7;
  const int i_loc = bid >> 3;            // 0..127
  const int mt = i_loc >> 2;             // 0..31
  const int nt = xcd * 4 + (i_loc & 3);  // 0..31
  const int tm = mt * BM;
  const int tn = nt * BN;

  const int t = threadIdx.x;
  const int l = t & 63;
  const int wv = t >> 6;
  const int wm = wv >> 1, wn = wv & 1;

  // A staging source: lane l covers row (l&31), k-bytes (l>>5)*16
  const uint8_t* gA = (const uint8_t*)xq + (size_t)tm * K_DIM +
                      (size_t)(l & 31) * K_DIM + ((l >> 5) << 4);
  // B fragment-major base for this wave's two n-frags
  const int nfrag0 = (tn >> 5) + wn * 2;
  const uint8_t* gB0 = wqf + ((size_t)(nfrag0 * 128) << 10) + l * 16;
  const uint8_t* gB1 = wqf + ((size_t)((nfrag0 + 1) * 128) << 10) + l * 16;

  int32x16 acc[4][2] = {};

  auto stageA = [&](int buf, int ktb) {
#pragma unroll
    for (int j = 0; j < 4; ++j) {
      const int bIdx = j * 4 + wv;  // fa = bIdx>>1, kb = bIdx&1
      __builtin_amdgcn_global_load_lds(
          (const __attribute__((address_space(1))) uint32_t*)(
              gA + (size_t)((bIdx >> 1) * 32) * K_DIM + (bIdx & 1) * 32 + ktb),
          (__attribute__((address_space(3))) uint32_t*)(
              &lds[buf][bIdx * 1024 + l * 16]),
          16, 0, 0);
    }
  };

  // load 4 B frags (n x kb) for K-slice pair starting at kslice s2
  auto loadB = [&](int32x4 (&b)[4], int s2) {
    b[0] = *(const int32x4*)(gB0 + ((size_t)(s2 + 0) << 10));
    b[1] = *(const int32x4*)(gB0 + ((size_t)(s2 + 1) << 10));
    b[2] = *(const int32x4*)(gB1 + ((size_t)(s2 + 0) << 10));
    b[3] = *(const int32x4*)(gB1 + ((size_t)(s2 + 1) << 10));
  };

  // one K-step: consume A(s) from LDS + B(s) from regs; prefetch A(s+2),
  // B(s+2) (B lands in the just-freed register set = same as bCur).
  auto do_step = [&](int s, int32x4 (&bCur)[4]) {
    const int buf = s % 3;
    const int sw = (s + 2) & 63;       // wrapped prefetch index
    stageA((s + 2) % 3, sw * BKB);     // 4 x global_load_lds
#pragma unroll
    for (int kb = 0; kb < 2; ++kb) {
      const uint8_t* base = &lds[buf][(wm * 8 + kb) * 1024 + l * 16];
      int32x4 a[4];
#pragma unroll
      for (int m = 0; m < 4; ++m) a[m] = *(const int32x4*)(base + m * 2048);
      __builtin_amdgcn_s_setprio(1);
#pragma unroll
      for (int m = 0; m < 4; ++m) {
        acc[m][0] = __builtin_amdgcn_mfma_i32_32x32x32_i8(a[m], bCur[kb],
                                                          acc[m][0], 0, 0, 0);
        acc[m][1] = __builtin_amdgcn_mfma_i32_32x32x32_i8(a[m], bCur[2 + kb],
                                                          acc[m][1], 0, 0, 0);
      }
      __builtin_amdgcn_s_setprio(0);
    }
    loadB(bCur, sw * 2);  // 4 global loads into freed regs (WAR keeps order)
    asm volatile("s_waitcnt vmcnt(8)" ::: "memory");  // A(s+1),B(s+1) landed
    __builtin_amdgcn_s_barrier();
  };

  const int nsteps = K_DIM / BKB;  // 64

  // prologue: A(0),A(1) staged; B(0)->X, B(1)->Y
  int32x4 bX[4], bY[4];
  stageA(0, 0);
  stageA(1, BKB);
  loadB(bX, 0);
  loadB(bY, 2);
  asm volatile("s_waitcnt vmcnt(4)" ::: "memory");  // A0,A1,B0 done
  __builtin_amdgcn_s_barrier();

  for (int s = 0; s < nsteps; s += 2) {
    do_step(s, bX);      // even steps use X; prefetch refills X for s+2
    do_step(s + 1, bY);  // odd steps use Y
  }
  asm volatile("s_waitcnt vmcnt(0)" ::: "memory");  // drain dead prefetches

  // epilogue: dequant + fp16-round, write f32
  const int colbase = tn + wn * 64;
  const int rowbase = tm + wm * 128 + 4 * (l >> 5);
#pragma unroll
  for (int m = 0; m < 4; ++m) {
#pragma unroll
    for (int n = 0; n < 2; ++n) {
      const int col = colbase + n * 32 + (l & 31);
      const float wsc = wscale[col];
#pragma unroll
      for (int j = 0; j < 16; ++j) {
        const int row = rowbase + m * 32 + (j & 3) + 8 * (j >> 2);
        const float val = (float)acc[m][n][j] * (xs[row] * wsc);
        out[(size_t)row * N_OUT + col] = __half2float(__float2half(val));
      }
    }
  }
}

extern "C" void kernel_launch(void* const* d_in, const int* in_sizes, int n_in,
                              void* d_out, int out_size, void* d_ws, size_t ws_size,
                              hipStream_t stream) {
  const float* x = (const float*)d_in[0];    // fp16 values as f32
  const int* w = (const int*)d_in[1];        // int4-range values as i32
  const float* wsc = (const float*)d_in[2];  // fp16 values as f32
  float* out = (float*)d_out;

  const int M = in_sizes[0] / K_DIM;  // 8192 tokens

  uint8_t* ws = (uint8_t*)d_ws;
  int8_t* xq = (int8_t*)ws;                              // M*K bytes
  uint8_t* wqf = ws + (size_t)M * K_DIM;                 // N*K bytes (frag-major)
  float* xs = (float*)(ws + (size_t)M * K_DIM + (size_t)N_OUT * K_DIM);

  quant_x<<<M, 256, 0, stream>>>(x, xq, xs);
  pack_w<<<(N_OUT * K_DIM / 16) / 256, 256, 0, stream>>>(w, (uint32_t*)wqf);
  gemm_w4a4<<<(M / BM) * (N_OUT / BN), 256, 0, stream>>>(
      xq, wqf, xs, wsc, out, M);
}